// Round 8
// baseline (219.123 us; speedup 1.0000x reference)
//
#include <hip/hip_runtime.h>

typedef short bf16x8 __attribute__((ext_vector_type(8)));
typedef float f32x4 __attribute__((ext_vector_type(4)));
typedef unsigned short u16x8 __attribute__((ext_vector_type(8)));

static __device__ __forceinline__ unsigned short f2bf(float f) {
  unsigned int x = __builtin_bit_cast(unsigned int, f);
  x += 0x7FFFu + ((x >> 16) & 1u);   // RNE
  return (unsigned short)(x >> 16);
}
// pack two floats' bf16 (round-half-away, matches original cvt3) into u32 (lo=a, hi=b)
static __device__ __forceinline__ unsigned int pk2bf(float a, float b) {
  unsigned int ia = __builtin_bit_cast(unsigned int, a) + 0x8000u;
  unsigned int ib = __builtin_bit_cast(unsigned int, b) + 0x8000u;
  return __builtin_amdgcn_perm(ib, ia, 0x07060302u);
}
// HW packed f32->bf16 (RNE), 1 instruction for 2 values: lo=a, hi=b
static __device__ __forceinline__ unsigned int cvtpk(float a, float b) {
  unsigned int r;
  asm("v_cvt_pk_bf16_f32 %0, %1, %2" : "=v"(r) : "v"(a), "v"(b));
  return r;
}
// async 16B global -> LDS
static __device__ __forceinline__ void gl2lds16(const unsigned short* g, unsigned short* l) {
  __builtin_amdgcn_global_load_lds(
      (const __attribute__((address_space(1))) unsigned int*)g,
      (__attribute__((address_space(3))) unsigned int*)l, 16, 0, 0);
}

// ------- 4x W [512k][512n] f32 -> WT [4][512n][512k] bf16 (z selects matrix) -------
__global__ __launch_bounds__(256) void wtrans4(const float* __restrict__ Wq, const float* __restrict__ Wk,
                                               const float* __restrict__ Wv, const float* __restrict__ Wo,
                                               unsigned short* __restrict__ WT) {
  __shared__ __align__(16) float T[64 * 68];
  const int z = blockIdx.z;
  const float* W = (z == 0) ? Wq : (z == 1) ? Wk : (z == 2) ? Wv : Wo;
  unsigned short* out = WT + (size_t)z * 512 * 512;
  const int k0 = blockIdx.x * 64, n0 = blockIdx.y * 64;
  const int tid = threadIdx.x;
#pragma unroll
  for (int i = 0; i < 4; ++i) {
    int chunk = i * 256 + tid;
    int row = chunk >> 4, fc = chunk & 15;
    *(float4*)(T + row * 68 + fc * 4) =
        *(const float4*)(W + (size_t)(k0 + row) * 512 + n0 + fc * 4);
  }
  __syncthreads();
#pragma unroll
  for (int i = 0; i < 2; ++i) {
    int chunk = i * 256 + tid;
    int nr = chunk >> 3, kc = chunk & 7;
    u16x8 v;
#pragma unroll
    for (int j = 0; j < 8; ++j) v[j] = f2bf(T[(kc * 8 + j) * 68 + nr]);
    *(u16x8*)(out + (size_t)(n0 + nr) * 512 + k0 + kc * 8) = v;
  }
}

// ---- fused QKV GEMM v3b: reads fp32 q/k/v DIRECTLY (cvt3 fused, pk2bf rounding
// bit-identical to the old cvt3) and for V-blocks (y>=8) writes transposed
// tau-permuted V^T DIRECTLY to vt with f2bf (bit-identical to old f2bf+vtrans).
// 128x128 tile, BK=32, 16 K-steps, 4 waves x 64x64, counted vmcnt pipeline.
__global__ __launch_bounds__(256) void gemm_qkv(const float* __restrict__ Aq,
                                                const float* __restrict__ Ak,
                                                const float* __restrict__ Av,
                                                const unsigned short* __restrict__ Bt,
                                                unsigned short* __restrict__ C,
                                                unsigned short* __restrict__ vt,
                                                float qscale) {
  __shared__ __align__(16) unsigned short Abuf[2][128 * 32];
  __shared__ __align__(16) unsigned short Bbuf[2][128 * 32];
  const int K = 512, LDC = 1536;
  const int y = blockIdx.y;
  const float* A32 = (y < 4) ? Aq : (y < 8) ? Ak : Av;
  const int tid = threadIdx.x;
  const int wid = tid >> 6, lane = tid & 63, quad = lane >> 4, li = lane & 15;
  const int bm = blockIdx.x * 128, bn = y * 128;
  const int wr = (wid >> 1) * 64, wc = (wid & 1) * 64;   // wave's 64x64 quadrant

  // staging geometry: 512 chunks (128 rows x 4 k-chunks), 2 per thread, swizzled src
  const int r0c = tid >> 2,         c0 = (tid & 3) ^ (r0c & 3);
  const int r1c = (256 + tid) >> 2, c1 = ((256 + tid) & 3) ^ (r1c & 3);
  const float* ga0 = A32 + (size_t)(bm + r0c) * K + c0 * 8;
  const float* ga1 = A32 + (size_t)(bm + r1c) * K + c1 * 8;
  const unsigned short* gb0 = Bt + (size_t)(bn + r0c) * K + c0 * 8;
  const unsigned short* gb1 = Bt + (size_t)(bn + r1c) * K + c1 * 8;
  const int oa0 = tid * 8, oa1 = (256 + tid) * 8;

  // prologue: A(0) -> regs -> Abuf[0]; issue A(1); issue B(0)
  float4 a0a = *(const float4*)(ga0);
  float4 a0b = *(const float4*)(ga0 + 4);
  float4 a1a = *(const float4*)(ga1);
  float4 a1b = *(const float4*)(ga1 + 4);
  ga0 += 32; ga1 += 32;
  asm volatile("s_waitcnt vmcnt(0)" ::: "memory");
  {
    uint4 w0, w1;
    w0.x = pk2bf(a0a.x, a0a.y); w0.y = pk2bf(a0a.z, a0a.w);
    w0.z = pk2bf(a0b.x, a0b.y); w0.w = pk2bf(a0b.z, a0b.w);
    w1.x = pk2bf(a1a.x, a1a.y); w1.y = pk2bf(a1a.z, a1a.w);
    w1.z = pk2bf(a1b.x, a1b.y); w1.w = pk2bf(a1b.z, a1b.w);
    *(uint4*)(&Abuf[0][oa0]) = w0;
    *(uint4*)(&Abuf[0][oa1]) = w1;
  }
  a0a = *(const float4*)(ga0); a0b = *(const float4*)(ga0 + 4);
  a1a = *(const float4*)(ga1); a1b = *(const float4*)(ga1 + 4);
  ga0 += 32; ga1 += 32;
  gl2lds16(gb0, &Bbuf[0][oa0]); gl2lds16(gb1, &Bbuf[0][oa1]);
  gb0 += 32; gb1 += 32;
  // outstanding entering loop: A(1) x4 (older), B(0) x2 (newer)

  f32x4 acc[4][4] = {};
  const int xo = (quad ^ (li & 3)) * 8;
  for (int s = 0; s < 16; ++s) {
    __builtin_amdgcn_s_barrier();                        // A: WAR on buf[(s+1)&1]
    if (s + 1 < 16) {
      int p = (s + 1) & 1;
      asm volatile("s_waitcnt vmcnt(2)" ::: "memory");   // A(s+1) regs landed (keep B(s))
      uint4 w0, w1;
      w0.x = pk2bf(a0a.x, a0a.y); w0.y = pk2bf(a0a.z, a0a.w);
      w0.z = pk2bf(a0b.x, a0b.y); w0.w = pk2bf(a0b.z, a0b.w);
      w1.x = pk2bf(a1a.x, a1a.y); w1.y = pk2bf(a1a.z, a1a.w);
      w1.z = pk2bf(a1b.x, a1b.y); w1.w = pk2bf(a1b.z, a1b.w);
      *(uint4*)(&Abuf[p][oa0]) = w0;
      *(uint4*)(&Abuf[p][oa1]) = w1;
      if (s + 2 < 16) {
        a0a = *(const float4*)(ga0); a0b = *(const float4*)(ga0 + 4);
        a1a = *(const float4*)(ga1); a1b = *(const float4*)(ga1 + 4);
        ga0 += 32; ga1 += 32;
      }
      gl2lds16(gb0, &Bbuf[p][oa0]); gl2lds16(gb1, &Bbuf[p][oa1]);
      gb0 += 32; gb1 += 32;
    }
    // drain B(s) only; keep A(s+2)+B(s+1) in flight
    if (s <= 13)      asm volatile("s_waitcnt vmcnt(6)" ::: "memory");
    else if (s == 14) asm volatile("s_waitcnt vmcnt(2)" ::: "memory");
    else              asm volatile("s_waitcnt vmcnt(0)" ::: "memory");
    asm volatile("s_waitcnt lgkmcnt(0)" ::: "memory");   // A-writes done (publish)
    __builtin_amdgcn_s_barrier();                        // B: publish tile s
    __builtin_amdgcn_sched_barrier(0);
    const unsigned short* As = &Abuf[s & 1][0];
    const unsigned short* Bs = &Bbuf[s & 1][0];
    bf16x8 af[4], bf[4];
#pragma unroll
    for (int t = 0; t < 4; ++t)
      af[t] = *(const bf16x8*)(As + (wr + t * 16 + li) * 32 + xo);
#pragma unroll
    for (int t = 0; t < 4; ++t)
      bf[t] = *(const bf16x8*)(Bs + (wc + t * 16 + li) * 32 + xo);
#pragma unroll
    for (int mt = 0; mt < 4; ++mt)
#pragma unroll
      for (int nt = 0; nt < 4; ++nt)
        acc[mt][nt] = __builtin_amdgcn_mfma_f32_16x16x32_bf16(af[mt], bf[nt], acc[mt][nt], 0, 0, 0);
  }

  if (y < 8) {
    const float scale = (y < 4) ? qscale : 1.0f;
#pragma unroll
    for (int mt = 0; mt < 4; ++mt)
#pragma unroll
      for (int nt = 0; nt < 4; ++nt) {
        int r0 = bm + wr + mt * 16 + quad * 4;
        int c  = bn + wc + nt * 16 + li;
#pragma unroll
        for (int r = 0; r < 4; ++r)
          C[(size_t)(r0 + r) * LDC + c] = f2bf(acc[mt][nt][r] * scale);
      }
  } else {
    // direct V^T write (tau-permuted), f2bf RNE = bit-identical to old f2bf+vtrans:
    // vt[(b*8+h)*64+d][kt*64 + p]; lane's 4 tokens are consecutive p (8 B store).
    const int tile_g = (bm + wr) >> 6;          // global 64-token tile
    const int bb = tile_g >> 6, kt = tile_g & 63;
#pragma unroll
    for (int mt = 0; mt < 4; ++mt) {
      int pb = (mt >> 1) * 32 + quad * 8 + (mt & 1) * 4;
#pragma unroll
      for (int nt = 0; nt < 4; ++nt) {
        int col = bn + wc + nt * 16 + li - 1024;   // v-dim 0..511
        int hh = col >> 6, dd = col & 63;
        uint2 w;
        w.x = (unsigned int)f2bf(acc[mt][nt][0]) | ((unsigned int)f2bf(acc[mt][nt][1]) << 16);
        w.y = (unsigned int)f2bf(acc[mt][nt][2]) | ((unsigned int)f2bf(acc[mt][nt][3]) << 16);
        *(uint2*)(vt + ((size_t)(bb * 8 + hh) * 64 + dd) * 4096 + kt * 64 + pb) = w;
      }
    }
  }
}

// ---- O-proj GEMM: out[8192][512] f32 = ob[8192][512] * WoT^T. (unchanged) ----
__global__ __launch_bounds__(256) void gemm_o(const unsigned short* __restrict__ A,
                                              const unsigned short* __restrict__ Bt,
                                              float* __restrict__ Cf) {
  __shared__ __align__(16) unsigned short Abuf[2][128 * 64];
  __shared__ __align__(16) unsigned short Bbuf[2][64 * 64];
  const int K = 512, LDC = 512;
  const int tid = threadIdx.x;
  const int wid = tid >> 6, lane = tid & 63, quad = lane >> 4, li = lane & 15;
  const int bm = blockIdx.x * 128, bn = blockIdx.y * 64;
  const int wm = wid * 32;
  const unsigned short* ga[4]; int oa[4];
  const unsigned short* gb[2]; int ob[2];
#pragma unroll
  for (int i = 0; i < 4; ++i) {
    int lam = i * 256 + wid * 64 + lane;
    int r = lam >> 3, c = (lam & 7) ^ (r & 7);
    ga[i] = A + (size_t)(bm + r) * K + c * 8;
    oa[i] = lam * 8;
  }
#pragma unroll
  for (int i = 0; i < 2; ++i) {
    int lam = i * 256 + wid * 64 + lane;
    int r = lam >> 3, c = (lam & 7) ^ (r & 7);
    gb[i] = Bt + (size_t)(bn + r) * K + c * 8;
    ob[i] = lam * 8;
  }
#pragma unroll
  for (int i = 0; i < 4; ++i) { gl2lds16(ga[i], &Abuf[0][oa[i]]); ga[i] += 64; }
#pragma unroll
  for (int i = 0; i < 2; ++i) { gl2lds16(gb[i], &Bbuf[0][ob[i]]); gb[i] += 64; }

  f32x4 acc[2][4] = {};
  const int sw = li & 7;
  for (int s = 0; s < 8; ++s) {
    __builtin_amdgcn_s_barrier();
    if (s + 1 < 8) {
      int p = (s + 1) & 1;
#pragma unroll
      for (int i = 0; i < 4; ++i) { gl2lds16(ga[i], &Abuf[p][oa[i]]); ga[i] += 64; }
#pragma unroll
      for (int i = 0; i < 2; ++i) { gl2lds16(gb[i], &Bbuf[p][ob[i]]); gb[i] += 64; }
      asm volatile("s_waitcnt vmcnt(6)" ::: "memory");
    } else {
      asm volatile("s_waitcnt vmcnt(0)" ::: "memory");
    }
    __builtin_amdgcn_s_barrier();
    __builtin_amdgcn_sched_barrier(0);
    const unsigned short* As = &Abuf[s & 1][0];
    const unsigned short* Bs = &Bbuf[s & 1][0];
#pragma unroll
    for (int kk = 0; kk < 2; ++kk) {
      bf16x8 af[2], bfr[4];
#pragma unroll
      for (int t = 0; t < 2; ++t)
        af[t] = *(const bf16x8*)(As + (wm + t * 16 + li) * 64 + (((kk * 4 + quad) ^ sw) * 8));
#pragma unroll
      for (int t = 0; t < 4; ++t)
        bfr[t] = *(const bf16x8*)(Bs + (t * 16 + li) * 64 + (((kk * 4 + quad) ^ sw) * 8));
#pragma unroll
      for (int mt = 0; mt < 2; ++mt)
#pragma unroll
        for (int nt = 0; nt < 4; ++nt)
          acc[mt][nt] = __builtin_amdgcn_mfma_f32_16x16x32_bf16(af[mt], bfr[nt], acc[mt][nt], 0, 0, 0);
    }
  }
#pragma unroll
  for (int mt = 0; mt < 2; ++mt)
#pragma unroll
    for (int nt = 0; nt < 4; ++nt) {
      int r0 = bm + wm + mt * 16 + quad * 4;
      int c  = bn + nt * 16 + li;
#pragma unroll
      for (int r = 0; r < 4; ++r)
        Cf[(size_t)(r0 + r) * LDC + c] = acc[mt][nt][r];
    }
}

// ---- flash attention v5 (unchanged, verified 94-95 us): in-block split-KV,
// 8 waves x 32q, NO-MAX softmax, LDS combine, in-register P via tau-permuted V. ----
__global__ __launch_bounds__(512, 2) void attn(const unsigned short* __restrict__ qkv,
                                               const unsigned short* __restrict__ vt,
                                               const int* __restrict__ mask,
                                               unsigned short* __restrict__ obuf) {
  // SM layout (shorts): Kb [par][hv][4096] = 16384 | Vb same = 16384 | Msk 256
  __shared__ __align__(16) unsigned short SM[33024];
  unsigned short* Kb = SM;
  unsigned short* Vb = SM + 16384;
  unsigned short* Mk = SM + 32768;
  const int qt = blockIdx.x, h = blockIdx.y, b = blockIdx.z;
  const int tid = threadIdx.x;
  const int wid = tid >> 6, lane = tid & 63, quad = lane >> 4, li = lane & 15;
  const int hv = wid >> 2;   // which KV half this wave computes
  const int wq = wid & 3;    // query group of 32
  const size_t tok0 = (size_t)b * 4096;

  if (tid < 256) {
    const int4* mp = (const int4*)(mask + b * 4096 + tid * 16);
    unsigned int bits = 0;
#pragma unroll
    for (int j = 0; j < 4; ++j) {
      int4 m4 = mp[j];
      bits |= (m4.x ? 1u : 0u) << (j * 4 + 0);
      bits |= (m4.y ? 1u : 0u) << (j * 4 + 1);
      bits |= (m4.z ? 1u : 0u) << (j * 4 + 2);
      bits |= (m4.w ? 1u : 0u) << (j * 4 + 3);
    }
    Mk[tid] = (unsigned short)bits;
  }

  // Q as B-operand: wave owns queries qt*128 + wq*32 + qg*16 + li (qg = 0,1)
  const unsigned short* qp0 = qkv + (tok0 + qt * 128 + wq * 32 + li) * 1536 + h * 64;
  const unsigned short* qp1 = qp0 + (size_t)16 * 1536;
  bf16x8 bq[2][2];
  bq[0][0] = *(const bf16x8*)(qp0 + quad * 8);
  bq[0][1] = *(const bf16x8*)(qp0 + 32 + quad * 8);
  bq[1][0] = *(const bf16x8*)(qp1 + quad * 8);
  bq[1][1] = *(const bf16x8*)(qp1 + 32 + quad * 8);

  // staging: all 512 threads; each stages 1 chunk of each of {K0,K1,V0,V1} per step
  const unsigned short* kbase = qkv + tok0 * 1536 + 512 + h * 64;
  const unsigned short* vbase = vt + (size_t)(b * 8 + h) * 64 * 4096;
  const int sr = tid >> 3, sc8 = ((tid & 7) ^ (sr & 7)) * 8;
  const unsigned short* gk0 = kbase + (size_t)sr * 1536 + sc8;                  // half 0
  const unsigned short* gk1 = kbase + (size_t)(2048 + sr) * 1536 + sc8;         // half 1
  const unsigned short* gv0 = vbase + (size_t)sr * 4096 + sc8;                  // half 0
  const unsigned short* gv1 = vbase + (size_t)sr * 4096 + 2048 + sc8;           // half 1
  const int ol = tid * 8;   // short offset of this thread's chunk within a tile

  gl2lds16(gk0, Kb + ol);          gl2lds16(gk1, Kb + 4096 + ol);
  gl2lds16(gv0, Vb + ol);          gl2lds16(gv1, Vb + 4096 + ol);
  gk0 += (size_t)64 * 1536; gk1 += (size_t)64 * 1536; gv0 += 64; gv1 += 64;

  f32x4 lacc[2] = {};
  f32x4 accO[2][4] = {};
  const int sw = li & 7;

  // publish Mk before first raw barrier (raw s_barrier doesn't drain lgkm)
  asm volatile("s_waitcnt lgkmcnt(0)" ::: "memory");

  for (int t = 0; t < 32; ++t) {
    __builtin_amdgcn_s_barrier();          // A: all waves done with buf (t+1)&1
    if (t < 31) {
      int p = (t + 1) & 1;
      unsigned short* kd = Kb + p * 8192;
      unsigned short* vd = Vb + p * 8192;
      gl2lds16(gk0, kd + ol);        gl2lds16(gk1, kd + 4096 + ol);
      gl2lds16(gv0, vd + ol);        gl2lds16(gv1, vd + 4096 + ol);
      gk0 += (size_t)64 * 1536; gk1 += (size_t)64 * 1536; gv0 += 64; gv1 += 64;
      asm volatile("s_waitcnt vmcnt(4)" ::: "memory");  // drain step t's loads only
    } else {
      asm volatile("s_waitcnt vmcnt(0)" ::: "memory");
    }
    __builtin_amdgcn_s_barrier();          // B: publish step t
    __builtin_amdgcn_sched_barrier(0);
    const unsigned short* Ks = Kb + (t & 1) * 8192 + hv * 4096;
    const unsigned short* Vs = Vb + (t & 1) * 8192 + hv * 4096;

    // S^T = K Q^T: lane = query li; keys kb*16 + quad*4 + r; K reads shared by both qg
    f32x4 s[2][4];
    __builtin_amdgcn_s_setprio(1);
#pragma unroll
    for (int kb = 0; kb < 4; ++kb) {
      const unsigned short* kr = Ks + (kb * 16 + li) * 64;
      bf16x8 ak0 = *(const bf16x8*)(kr + ((quad ^ sw) * 8));
      bf16x8 ak1 = *(const bf16x8*)(kr + (((4 + quad) ^ sw) * 8));
#pragma unroll
      for (int qg = 0; qg < 2; ++qg) {
        f32x4 z = {};
        z = __builtin_amdgcn_mfma_f32_16x16x32_bf16(ak0, bq[qg][0], z, 0, 0, 0);
        z = __builtin_amdgcn_mfma_f32_16x16x32_bf16(ak1, bq[qg][1], z, 0, 0, 0);
        s[qg][kb] = z;
      }
    }
    __builtin_amdgcn_s_setprio(0);
    int tt = hv * 32 + t;
    unsigned long long mbits = *(const unsigned long long*)(Mk + tt * 4);
    if (mbits != ~0ull) {
#pragma unroll
      for (int kb = 0; kb < 4; ++kb)
#pragma unroll
        for (int r = 0; r < 4; ++r) {
          int key = kb * 16 + quad * 4 + r;
          if (!((mbits >> key) & 1ull)) { s[0][kb][r] = -1e30f; s[1][kb][r] = -1e30f; }
        }
    }
    // p = exp2(s); partial l; pack in-register into PV A-fragments (tau-aligned)
    bf16x8 pf[2][2];
#pragma unroll
    for (int qg = 0; qg < 2; ++qg) {
#pragma unroll
      for (int kb = 0; kb < 4; ++kb) {
#pragma unroll
        for (int r = 0; r < 4; ++r) s[qg][kb][r] = __builtin_amdgcn_exp2f(s[qg][kb][r]);
        lacc[qg] += s[qg][kb];
      }
      uint4 u0, u1;
      u0.x = cvtpk(s[qg][0][0], s[qg][0][1]); u0.y = cvtpk(s[qg][0][2], s[qg][0][3]);
      u0.z = cvtpk(s[qg][1][0], s[qg][1][1]); u0.w = cvtpk(s[qg][1][2], s[qg][1][3]);
      u1.x = cvtpk(s[qg][2][0], s[qg][2][1]); u1.y = cvtpk(s[qg][2][2], s[qg][2][3]);
      u1.z = cvtpk(s[qg][3][0], s[qg][3][1]); u1.w = cvtpk(s[qg][3][2], s[qg][3][3]);
      pf[qg][0] = __builtin_bit_cast(bf16x8, u0);
      pf[qg][1] = __builtin_bit_cast(bf16x8, u1);
    }
    // O += P V ; V reads shared by both qg
    __builtin_amdgcn_s_setprio(1);
#pragma unroll
    for (int dc = 0; dc < 4; ++dc) {
      const unsigned short* vr = Vs + (dc * 16 + li) * 64;
      bf16x8 bv0 = *(const bf16x8*)(vr + ((quad ^ sw) * 8));
      bf16x8 bv1 = *(const bf16x8*)(vr + (((4 + quad) ^ sw) * 8));
#pragma unroll
      for (int qg = 0; qg < 2; ++qg) {
        accO[qg][dc] = __builtin_amdgcn_mfma_f32_16x16x32_bf16(pf[qg][0], bv0, accO[qg][dc], 0, 0, 0);
        accO[qg][dc] = __builtin_amdgcn_mfma_f32_16x16x32_bf16(pf[qg][1], bv1, accO[qg][dc], 0, 0, 0);
      }
    }
    __builtin_amdgcn_s_setprio(0);
  }

  // ---- combine halves: waves 4-7 dump partials to LDS; waves 0-3 add + store ----
  __syncthreads();                       // K/V buffers dead; reuse as f32 scratch (40 KB)
  float* scr = (float*)SM;               // layout: scr[j*256 + wq*64 + lane], j in 0..39
  if (hv == 1) {
#pragma unroll
    for (int qg = 0; qg < 2; ++qg) {
#pragma unroll
      for (int dc = 0; dc < 4; ++dc)
#pragma unroll
        for (int r = 0; r < 4; ++r)
          scr[(qg * 16 + dc * 4 + r) * 256 + wq * 64 + lane] = accO[qg][dc][r];
#pragma unroll
      for (int r = 0; r < 4; ++r)
        scr[(32 + qg * 4 + r) * 256 + wq * 64 + lane] = lacc[qg][r];
    }
  }
  __syncthreads();
  if (hv == 0) {
#pragma unroll
    for (int qg = 0; qg < 2; ++qg) {
#pragma unroll
      for (int dc = 0; dc < 4; ++dc)
#pragma unroll
        for (int r = 0; r < 4; ++r)
          accO[qg][dc][r] += scr[(qg * 16 + dc * 4 + r) * 256 + wq * 64 + lane];
#pragma unroll
      for (int r = 0; r < 4; ++r)
        lacc[qg][r] += scr[(32 + qg * 4 + r) * 256 + wq * 64 + lane];
    }
    // full l per query, then normalize + store
#pragma unroll
    for (int qg = 0; qg < 2; ++qg) {
      float lt = lacc[qg][0] + lacc[qg][1] + lacc[qg][2] + lacc[qg][3];
      lt += __shfl_xor(lt, 16);
      lt += __shfl_xor(lt, 32);
      float lv0 = 1.f / __shfl(lt, quad * 4 + 0);
      float lv1 = 1.f / __shfl(lt, quad * 4 + 1);
      float lv2 = 1.f / __shfl(lt, quad * 4 + 2);
      float lv3 = 1.f / __shfl(lt, quad * 4 + 3);
      size_t r0q = tok0 + qt * 128 + wq * 32 + qg * 16 + quad * 4;
#pragma unroll
      for (int dc = 0; dc < 4; ++dc) {
        size_t col = h * 64 + dc * 16 + li;
        obuf[(r0q + 0) * 512 + col] = f2bf(accO[qg][dc][0] * lv0);
        obuf[(r0q + 1) * 512 + col] = f2bf(accO[qg][dc][1] * lv1);
        obuf[(r0q + 2) * 512 + col] = f2bf(accO[qg][dc][2] * lv2);
        obuf[(r0q + 3) * 512 + col] = f2bf(accO[qg][dc][3] * lv3);
      }
    }
  }
}

extern "C" void kernel_launch(void* const* d_in, const int* in_sizes, int n_in,
                              void* d_out, int out_size, void* d_ws, size_t ws_size,
                              hipStream_t stream) {
  const float* q  = (const float*)d_in[0];
  const float* k  = (const float*)d_in[1];
  const float* v  = (const float*)d_in[2];
  const int* mask = (const int*)d_in[3];
  const float* Wq = (const float*)d_in[4];
  const float* Wk = (const float*)d_in[5];
  const float* Wv = (const float*)d_in[6];
  const float* Wo = (const float*)d_in[7];
  float* out = (float*)d_out;

  char* ws = (char*)d_ws;
  const size_t SA = (size_t)8192 * 512 * 2;   // 8 MB
  unsigned short* vtb  = (unsigned short*)(ws);                   // 8 MB (per-head V^T)
  unsigned short* ob   = (unsigned short*)(ws + SA);              // 8 MB (attn out bf16)
  unsigned short* qkvh = (unsigned short*)(ws + 3 * SA);          // 24 MB
  unsigned short* wAll = (unsigned short*)(ws + 6 * SA);          // 2 MB
  unsigned short* woT  = wAll + (size_t)3 * 512 * 512;

  dim3 wg(8, 8, 4);
  wtrans4<<<wg, 256, 0, stream>>>(Wq, Wk, Wv, Wo, wAll);
  const float qscale = 0.125f * 1.44269504f;  // 1/sqrt(64) * log2(e)
  dim3 gq(64, 12);
  gemm_qkv<<<gq, 256, 0, stream>>>(q, k, v, wAll, qkvh, vtb, qscale);
  dim3 ag(32, 8, 2);
  attn<<<ag, 512, 0, stream>>>(qkvh, vtb, mask, ob);
  dim3 go(64, 8);
  gemm_o<<<go, 256, 0, stream>>>(ob, woT, out);
}